// Round 4
// baseline (241.062 us; speedup 1.0000x reference)
//
#include <hip/hip_runtime.h>
#include <hip/hip_bf16.h>

typedef __hip_bfloat16 bf16;
typedef _Float16 f16;
typedef __attribute__((ext_vector_type(8))) short bf16x8;
typedef __attribute__((ext_vector_type(8))) _Float16 f16x8;
typedef __attribute__((ext_vector_type(2))) _Float16 f16x2;
typedef __attribute__((ext_vector_type(4))) float f32x4;
typedef __attribute__((ext_vector_type(4))) unsigned int u32x4;
typedef __attribute__((ext_vector_type(2))) unsigned int u32x2;

#define B_ 4
#define N_ 4096
#define C_ 256
#define H_ 4
#define D_ 64
#define KLN 0.18033688011112042f   /* 0.125 * log2(e): folded into Q */

#if __has_builtin(__builtin_amdgcn_exp2f)
#define EXP2(x) __builtin_amdgcn_exp2f(x)
#else
#define EXP2(x) exp2f(x)
#endif
#if __has_builtin(__builtin_amdgcn_rcpf)
#define RCP(x) __builtin_amdgcn_rcpf(x)
#else
#define RCP(x) (1.0f / (x))
#endif

// two fp32 -> packed bf16 pair (round-half-up; SAME rounding as the old cast
// kernel so all MFMA inputs stay bitwise identical across rounds)
__device__ inline unsigned int pk2(float a, float b) {
    unsigned int ua = __builtin_bit_cast(unsigned int, a) + 0x8000u;
    unsigned int ub = __builtin_bit_cast(unsigned int, b) + 0x8000u;
    return (ua >> 16) | (ub & 0xffff0000u);
}
// two fp32 -> packed f16 pair (single v_cvt_pkrtz_f16_f32)
__device__ inline unsigned int pkh2(float a, float b) {
#if __has_builtin(__builtin_amdgcn_cvt_pkrtz)
    return __builtin_bit_cast(unsigned int, __builtin_amdgcn_cvt_pkrtz(a, b));
#else
    f16x2 h = { (f16)a, (f16)b };
    return __builtin_bit_cast(unsigned int, h);
#endif
}
// 8 fp32 -> bf16x8 via pk2 (bitwise identical to cast_bf16 + bf16 reload)
__device__ inline bf16x8 cvt8pk(const float* __restrict__ p) {
    f32x4 a = *reinterpret_cast<const f32x4*>(p);
    f32x4 b = *reinterpret_cast<const f32x4*>(p + 4);
    u32x4 o = { pk2(a[0], a[1]), pk2(a[2], a[3]),
                pk2(b[0], b[1]), pk2(b[2], b[3]) };
    return __builtin_bit_cast(bf16x8, o);
}

// ---------------------------------------------------------------------------
// QKV projection from fp32 inputs (cast kernel fused away). W is staged into
// LDS as bf16 (pk2-converted during the stage) once per 128-row m-tile; x is
// converted per-fragment with the same pk2 rounding. Q pre-scaled by KLN;
// V -> [B,H,D,N] f16. Q/K use swapped MFMA operands -> transposed accumulator
// -> u32x2 stores. XCD swizzle groups the 12 n-tiles of one m-tile per XCD.
// ---------------------------------------------------------------------------
__global__ __launch_bounds__(256, 2) void qkv_fast(const float* __restrict__ x,
                                                   const float* __restrict__ w,
                                                   bf16* __restrict__ qw,
                                                   bf16* __restrict__ kw,
                                                   f16* __restrict__ vtw)
{
    __shared__ short w_s[64][264];
    const int tid  = threadIdx.x;
    const int lane = tid & 63;
    const int wav  = tid >> 6;
    const int quad = lane >> 4;
    const int l16  = lane & 15;
    const int bid = (blockIdx.x & 7) * 192 + (blockIdx.x >> 3);   // 1536 = 8*192
    const int mt = bid / 12, nb = bid % 12;
    const int m0 = mt * 128, n0 = nb * 64;

    {
        const int row = tid >> 2, cb = (tid & 3) * 64;
        const float* src = w + (size_t)(n0 + row) * C_ + cb;
#pragma unroll
        for (int i = 0; i < 8; ++i) {
            f32x4 a = *reinterpret_cast<const f32x4*>(src + i * 8);
            f32x4 b = *reinterpret_cast<const f32x4*>(src + i * 8 + 4);
            u32x4 ov = { pk2(a[0], a[1]), pk2(a[2], a[3]),
                         pk2(b[0], b[1]), pk2(b[2], b[3]) };
            *reinterpret_cast<u32x4*>(&w_s[row][cb + i * 8]) = ov;
        }
    }
    __syncthreads();

#pragma unroll
    for (int half = 0; half < 2; ++half) {
        const int mh = m0 + half * 64;
        f32x4 acc[4] = {{0,0,0,0},{0,0,0,0},{0,0,0,0},{0,0,0,0}};
        const float* xrow = x + (size_t)(mh + wav * 16 + l16) * C_ + quad * 8;
        if (nb < 8) {        // Q/K: transposed accumulator (swapped operands)
#pragma unroll
            for (int k0 = 0; k0 < C_; k0 += 32) {
                bf16x8 a = cvt8pk(xrow + k0);
#pragma unroll
                for (int nt = 0; nt < 4; ++nt) {
                    bf16x8 b = *reinterpret_cast<const bf16x8*>(&w_s[nt * 16 + l16][k0 + quad * 8]);
                    acc[nt] = __builtin_amdgcn_mfma_f32_16x16x32_bf16(b, a, acc[nt], 0, 0, 0);
                }
            }
        } else {             // V: normal orientation (store wants n-contiguous)
#pragma unroll
            for (int k0 = 0; k0 < C_; k0 += 32) {
                bf16x8 a = cvt8pk(xrow + k0);
#pragma unroll
                for (int nt = 0; nt < 4; ++nt) {
                    bf16x8 b = *reinterpret_cast<const bf16x8*>(&w_s[nt * 16 + l16][k0 + quad * 8]);
                    acc[nt] = __builtin_amdgcn_mfma_f32_16x16x32_bf16(a, b, acc[nt], 0, 0, 0);
                }
            }
        }

        const int bb = mh >> 12;
        const int nbase = (mh + wav * 16) & (N_ - 1);
        if (nb < 4) {                            // Q (scaled): row n = nbase+l16
            bf16* dst = qw + (((size_t)bb * H_ + nb) * N_ + nbase + l16) * D_;
#pragma unroll
            for (int nt = 0; nt < 4; ++nt) {
                u32x2 wv = { pk2(acc[nt][0] * KLN, acc[nt][1] * KLN),
                             pk2(acc[nt][2] * KLN, acc[nt][3] * KLN) };
                *reinterpret_cast<u32x2*>(dst + nt * 16 + quad * 4) = wv;
            }
        } else if (nb < 8) {                     // K
            bf16* dst = kw + (((size_t)bb * H_ + (nb - 4)) * N_ + nbase + l16) * D_;
#pragma unroll
            for (int nt = 0; nt < 4; ++nt) {
                u32x2 wv = { pk2(acc[nt][0], acc[nt][1]),
                             pk2(acc[nt][2], acc[nt][3]) };
                *reinterpret_cast<u32x2*>(dst + nt * 16 + quad * 4) = wv;
            }
        } else {                                 // V transposed, f16
            const int h = nb - 8;
#pragma unroll
            for (int nt = 0; nt < 4; ++nt) {
                int d = nt * 16 + l16;
                u32x2 wv;
                wv.x = pkh2(acc[nt][0], acc[nt][1]);
                wv.y = pkh2(acc[nt][2], acc[nt][3]);
                *reinterpret_cast<u32x2*>(
                    vtw + (((size_t)bb * H_ + h) * D_ + d) * N_ + nbase + quad * 4) = wv;
            }
        }
    }
}

// ---------------------------------------------------------------------------
// Flash attention v8: no LDS, no barriers, no DMA in the main loop.
//
// Round-3 counters showed MfmaUtil 37% + VALUBusy 46% with ~no overlap: the
// per-tile __syncthreads lockstepped all waves into the same {QK | exp | PV}
// phase, serializing the matrix and VALU pipes. K/V are L2-resident (1.5 MB
// per head, 2 heads/XCD via the swizzle), so v8 drops the global->LDS->reg
// path entirely: each wave loads its K/V fragments global->register,
// single-buffered, reloading each fragment right after its last use (the
// register anti-dependency pins the issue point; L2 latency ~200-300 cyc is
// covered by the remaining ~2000 cyc of tile compute). Waves never sync in
// the loop -> they drift, and exp2/pack VALU overlaps MFMA across (and
// within) waves. The pi row-permutation moves into the K load address.
// Arithmetic is bit-identical to v7 (pure data-movement change).
// Block = 4 waves = 2 q-subtiles (64 rows, 4 q-groups) x 2 j-halves.
// Grid 512 = 2 blocks/CU (VGPR ~220 -> 2 waves/SIMD).
// ---------------------------------------------------------------------------
__global__ __launch_bounds__(256, 2) void attn(const bf16* __restrict__ q,
                                               const bf16* __restrict__ k,
                                               const f16* __restrict__ vt,
                                               bf16* __restrict__ o)
{
    __shared__ float mrg[8832];      // j-half merge buffer only (~34.5 KB)

    const int tid  = threadIdx.x;
    const int lane = tid & 63;
    const int wav  = tid >> 6;       // 0..3
    const int quad = lane >> 4;
    const int l16  = lane & 15;
    const int sub  = wav & 1;        // 64-row q-slice within the 128-row tile
    const int jh   = wav >> 1;       // j-half

    const int wg = (blockIdx.x & 7) * 64 + (blockIdx.x >> 3);  // XCD swizzle
    const int bh = wg >> 5;
    const int qt = wg & 31;
    const int bb = bh >> 2, h = bh & 3;

    const bf16* qp = q  + (size_t)bh * N_ * D_;
    const bf16* kp = k  + (size_t)bh * N_ * D_;
    const f16*  vp = vt + (size_t)bh * D_ * N_;

    const int qbase = qt * 128 + sub * 64;
    bf16x8 qb[4][2];
#pragma unroll
    for (int qg = 0; qg < 4; ++qg)
#pragma unroll
        for (int ks = 0; ks < 2; ++ks)
            qb[qg][ks] = *reinterpret_cast<const bf16x8*>(
                qp + (size_t)(qbase + qg * 16 + l16) * D_ + ks * 32 + quad * 8);

    // pi-permuted K row per (nt): physical S^T row nt*16+l16 holds logical
    // j-row pi(nt*16+l16), which puts S^T output slots in PV k-slot order.
    int krow[4];
#pragma unroll
    for (int nt = 0; nt < 4; ++nt) {
        const int rho = nt * 16 + l16;
        krow[nt] = (rho & 32) | ((rho & 12) << 1) | ((rho & 16) >> 2) | (rho & 3);
    }

    f32x4 oacc[4][4];
    f32x4 lv[4];                    // per-lane f32 l partials (this quad's j's)
#pragma unroll
    for (int qg = 0; qg < 4; ++qg) {
        lv[qg] = (f32x4){0, 0, 0, 0};
#pragma unroll
        for (int dt = 0; dt < 4; ++dt) oacc[qg][dt] = (f32x4){0, 0, 0, 0};
    }

    const int j00 = jh * 2048;

    // single-buffered K/V fragment registers; preload tile 0
    bf16x8 kf[4][2];
    f16x8  vf[2][4];
#pragma unroll
    for (int nt = 0; nt < 4; ++nt)
#pragma unroll
        for (int ks = 0; ks < 2; ++ks)
            kf[nt][ks] = *reinterpret_cast<const bf16x8*>(
                kp + (size_t)(j00 + krow[nt]) * D_ + ks * 32 + quad * 8);
#pragma unroll
    for (int ks = 0; ks < 2; ++ks)
#pragma unroll
        for (int dt = 0; dt < 4; ++dt)
            vf[ks][dt] = *reinterpret_cast<const f16x8*>(
                vp + (size_t)(dt * 16 + l16) * N_ + j00 + (ks * 4 + quad) * 8);

    for (int t = 0; t < 32; ++t) {
        const int jn = j00 + (t + 1) * 64;   // next tile base

        // S^T = K.Q^T (4 q-groups share each K fragment); exp2 -> pb in regs
        f16x8 pb[4][2];
#pragma unroll
        for (int nt = 0; nt < 4; ++nt) {
            const bf16x8 k0 = kf[nt][0];
            const bf16x8 k1 = kf[nt][1];
#pragma unroll
            for (int qg = 0; qg < 4; ++qg) {
                f32x4 sv = __builtin_amdgcn_mfma_f32_16x16x32_bf16(
                    k0, qb[qg][0], (f32x4){0.f, 0.f, 0.f, 0.f}, 0, 0, 0);
                sv = __builtin_amdgcn_mfma_f32_16x16x32_bf16(
                    k1, qb[qg][1], sv, 0, 0, 0);
                f32x4 pa = { EXP2(sv[0]), EXP2(sv[1]), EXP2(sv[2]), EXP2(sv[3]) };
                u32x2 pw = { pkh2(pa[0], pa[1]), pkh2(pa[2], pa[3]) };
                if (nt & 1)
                    *(reinterpret_cast<u32x2*>(&pb[qg][nt >> 1]) + 1) = pw;
                else
                    *(reinterpret_cast<u32x2*>(&pb[qg][nt >> 1]) + 0) = pw;
                lv[qg] += pa;
            }
            // kf[nt] dead after the qg loop: reload for t+1 (anti-dep pins
            // this after the MFMAs; lands during exp/PV of this tile)
            if (t < 31) {
                kf[nt][0] = *reinterpret_cast<const bf16x8*>(
                    kp + (size_t)(jn + krow[nt]) * D_ + quad * 8);
                kf[nt][1] = *reinterpret_cast<const bf16x8*>(
                    kp + (size_t)(jn + krow[nt]) * D_ + 32 + quad * 8);
            }
        }

        // O^T += V^T . P^T; reload each vf right after its last use
#pragma unroll
        for (int ks = 0; ks < 2; ++ks)
#pragma unroll
            for (int dt = 0; dt < 4; ++dt) {
                const f16x8 va = vf[ks][dt];
#pragma unroll
                for (int qg = 0; qg < 4; ++qg)
                    oacc[qg][dt] = __builtin_amdgcn_mfma_f32_16x16x32_f16(
                        va, pb[qg][ks], oacc[qg][dt], 0, 0, 0);
                if (t < 31)
                    vf[ks][dt] = *reinterpret_cast<const f16x8*>(
                        vp + (size_t)(dt * 16 + l16) * N_ + jn + (ks * 4 + quad) * 8);
            }
    }

    // l: horizontal sum + butterfly across the 4 quads (same l16 = same q-row)
    float lr[4];
#pragma unroll
    for (int qg = 0; qg < 4; ++qg) {
        float l = (lv[qg][0] + lv[qg][1]) + (lv[qg][2] + lv[qg][3]);
        l += __shfl_xor(l, 16);
        l += __shfl_xor(l, 32);
        lr[qg] = l;
    }

    // ---- merge j-halves (exact: O and l add) via lane-to-lane LDS slots ----
    const int slot = (sub * 64 + lane) * 69;       // odd stride: no conflicts
    __syncthreads();
    if (jh == 1) {
#pragma unroll
        for (int qg = 0; qg < 4; ++qg) {
#pragma unroll
            for (int dt = 0; dt < 4; ++dt)
#pragma unroll
                for (int e = 0; e < 4; ++e)
                    mrg[slot + qg * 17 + dt * 4 + e] = oacc[qg][dt][e];
            mrg[slot + qg * 17 + 16] = lr[qg];
        }
    }
    __syncthreads();
    if (jh == 0) {
#pragma unroll
        for (int qg = 0; qg < 4; ++qg) {
            const float rl = RCP(lr[qg] + mrg[slot + qg * 17 + 16]);
            const size_t obase = ((size_t)bb * N_ + qbase + qg * 16 + l16) * C_ + h * D_;
#pragma unroll
            for (int dt = 0; dt < 4; ++dt) {
                float v0 = (oacc[qg][dt][0] + mrg[slot + qg * 17 + dt * 4 + 0]) * rl;
                float v1 = (oacc[qg][dt][1] + mrg[slot + qg * 17 + dt * 4 + 1]) * rl;
                float v2 = (oacc[qg][dt][2] + mrg[slot + qg * 17 + dt * 4 + 2]) * rl;
                float v3 = (oacc[qg][dt][3] + mrg[slot + qg * 17 + dt * 4 + 3]) * rl;
                u32x2 wv = { pk2(v0, v1), pk2(v2, v3) };
                *reinterpret_cast<u32x2*>(o + obase + dt * 16 + quad * 4) = wv;
            }
        }
    }
}

// ---------------------------------------------------------------------------
// Output projection from fp32 W (pk2-converted during the LDS stage), staged
// once per 128-row m-tile. Swapped MFMA operands -> transposed accumulator
// -> f32x4 stores.
// ---------------------------------------------------------------------------
__global__ __launch_bounds__(256, 2) void out_proj_fast(const bf16* __restrict__ ov,
                                                        const float* __restrict__ w,
                                                        const float* __restrict__ bias,
                                                        float* __restrict__ out)
{
    __shared__ short w_s[64][264];
    const int tid  = threadIdx.x;
    const int lane = tid & 63;
    const int wav  = tid >> 6;
    const int quad = lane >> 4;
    const int l16  = lane & 15;
    const int bid = (blockIdx.x & 7) * 64 + (blockIdx.x >> 3);   // 512 = 8*64
    const int m0 = (bid >> 2) * 128;
    const int n0 = (bid & 3) * 64;

    {
        const int row = tid >> 2, cb = (tid & 3) * 64;
        const float* src = w + (size_t)(n0 + row) * C_ + cb;
#pragma unroll
        for (int i = 0; i < 8; ++i) {
            f32x4 a = *reinterpret_cast<const f32x4*>(src + i * 8);
            f32x4 b = *reinterpret_cast<const f32x4*>(src + i * 8 + 4);
            u32x4 ov2 = { pk2(a[0], a[1]), pk2(a[2], a[3]),
                          pk2(b[0], b[1]), pk2(b[2], b[3]) };
            *reinterpret_cast<u32x4*>(&w_s[row][cb + i * 8]) = ov2;
        }
    }
    __syncthreads();

#pragma unroll
    for (int half = 0; half < 2; ++half) {
        const int mh = m0 + half * 64;
        f32x4 acc[4] = {{0,0,0,0},{0,0,0,0},{0,0,0,0},{0,0,0,0}};
        const bf16* orow = ov + (size_t)(mh + wav * 16 + l16) * C_ + quad * 8;
#pragma unroll
        for (int k0 = 0; k0 < C_; k0 += 32) {
            bf16x8 a = *reinterpret_cast<const bf16x8*>(orow + k0);
#pragma unroll
            for (int nt = 0; nt < 4; ++nt) {
                bf16x8 b = *reinterpret_cast<const bf16x8*>(&w_s[nt * 16 + l16][k0 + quad * 8]);
                acc[nt] = __builtin_amdgcn_mfma_f32_16x16x32_bf16(b, a, acc[nt], 0, 0, 0);
            }
        }
        const int m = mh + wav * 16 + l16;
#pragma unroll
        for (int nt = 0; nt < 4; ++nt) {
            const int oc0 = n0 + nt * 16 + quad * 4;
            f32x4 bv = *reinterpret_cast<const f32x4*>(bias + oc0);
            f32x4 ovv = acc[nt] + bv;
            *reinterpret_cast<f32x4*>(out + (size_t)m * C_ + oc0) = ovv;
        }
    }
}

extern "C" void kernel_launch(void* const* d_in, const int* in_sizes, int n_in,
                              void* d_out, int out_size, void* d_ws, size_t ws_size,
                              hipStream_t stream) {
    const float* x      = (const float*)d_in[0];
    const float* w_qkv  = (const float*)d_in[1];
    const float* w_proj = (const float*)d_in[2];
    const float* b_proj = (const float*)d_in[3];
    float* out = (float*)d_out;

    const size_t qkv_elems = (size_t)B_ * H_ * N_ * D_;   // 4,194,304
    bf16* q_ws  = (bf16*)d_ws;
    bf16* k_ws  = q_ws  + qkv_elems;
    f16*  vt_ws = (f16*)(k_ws + qkv_elems);
    bf16* o_ws  = (bf16*)(vt_ws + qkv_elems);

    qkv_fast     <<<1536, 256, 0, stream>>>(x, w_qkv, q_ws, k_ws, vt_ws);
    attn         <<< 512, 256, 0, stream>>>(q_ws, k_ws, vt_ws, o_ws);
    out_proj_fast<<< 512, 256, 0, stream>>>(o_ws, w_proj, b_proj, out);
}

// Round 6
// 199.818 us; speedup vs baseline: 1.2064x; 1.2064x over previous
//
#include <hip/hip_runtime.h>
#include <hip/hip_bf16.h>

typedef __hip_bfloat16 bf16;
typedef _Float16 f16;
typedef __attribute__((ext_vector_type(8))) short bf16x8;
typedef __attribute__((ext_vector_type(8))) _Float16 f16x8;
typedef __attribute__((ext_vector_type(2))) _Float16 f16x2;
typedef __attribute__((ext_vector_type(4))) float f32x4;
typedef __attribute__((ext_vector_type(4))) unsigned int u32x4;
typedef __attribute__((ext_vector_type(2))) unsigned int u32x2;

#define B_ 4
#define N_ 4096
#define C_ 256
#define H_ 4
#define D_ 64
#define KLN 0.18033688011112042f   /* 0.125 * log2(e): folded into Q */

#if __has_builtin(__builtin_amdgcn_exp2f)
#define EXP2(x) __builtin_amdgcn_exp2f(x)
#else
#define EXP2(x) exp2f(x)
#endif
#if __has_builtin(__builtin_amdgcn_rcpf)
#define RCP(x) __builtin_amdgcn_rcpf(x)
#else
#define RCP(x) (1.0f / (x))
#endif

// direct global->LDS DMA, 16B per lane. LDS dest = wave-uniform base + lane*16.
__device__ inline void load_lds16(const void* g, void* l) {
#if __has_builtin(__builtin_amdgcn_global_load_lds)
    __builtin_amdgcn_global_load_lds(
        (const __attribute__((address_space(1))) unsigned int*)g,
        (__attribute__((address_space(3))) unsigned int*)l, 16, 0, 0);
#else
    int ln = __lane_id();
    ((u32x4*)l)[ln] = *((const u32x4*)g);   // fallback (not used on gfx950)
#endif
}

// two fp32 -> packed bf16 pair (round-half-up)
__device__ inline unsigned int pk2(float a, float b) {
    unsigned int ua = __builtin_bit_cast(unsigned int, a) + 0x8000u;
    unsigned int ub = __builtin_bit_cast(unsigned int, b) + 0x8000u;
    return (ua >> 16) | (ub & 0xffff0000u);
}
// two fp32 -> packed f16 pair (single v_cvt_pkrtz_f16_f32)
__device__ inline unsigned int pkh2(float a, float b) {
#if __has_builtin(__builtin_amdgcn_cvt_pkrtz)
    return __builtin_bit_cast(unsigned int, __builtin_amdgcn_cvt_pkrtz(a, b));
#else
    f16x2 h = { (f16)a, (f16)b };
    return __builtin_bit_cast(unsigned int, h);
#endif
}

// ---------------------------------------------------------------------------
// Prep: cast x, w_qkv, w_proj fp32 -> bf16 (memory-bound). Restored: r4's
// fusion of this into qkv cost +9us (fp32 x reads + per-fragment cvt).
// ---------------------------------------------------------------------------
__global__ __launch_bounds__(256) void cast_bf16(const float* __restrict__ x,
                                                 const float* __restrict__ wq,
                                                 const float* __restrict__ wp,
                                                 bf16* __restrict__ xb,
                                                 bf16* __restrict__ wqb,
                                                 bf16* __restrict__ wpb)
{
    int bid = blockIdx.x;
    const float* s; bf16* d; int base;
    if (bid < 2048)      { s = x;  d = xb;  base = bid * 2048; }
    else if (bid < 2144) { s = wq; d = wqb; base = (bid - 2048) * 2048; }
    else                 { s = wp; d = wpb; base = (bid - 2144) * 2048; }
    int i = base + threadIdx.x * 8;
    f32x4 a = *reinterpret_cast<const f32x4*>(s + i);
    f32x4 b = *reinterpret_cast<const f32x4*>(s + i + 4);
    u32x4 o;
    o.x = pk2(a[0], a[1]); o.y = pk2(a[2], a[3]);
    o.z = pk2(b[0], b[1]); o.w = pk2(b[2], b[3]);
    *reinterpret_cast<u32x4*>(d + i) = o;
}

// ---------------------------------------------------------------------------
// QKV projection, W staged in LDS once per 128-row m-tile. Q pre-scaled by
// KLN; V -> [B,H,D,N] f16 via an LDS transpose so the global store is
// 16B-coalesced rows (the old direct store wrote 8B granules at 8KB stride:
// ~8x write amplification on 8MB). launch_bounds(256,3): LDS 42.5KB -> 3
// blocks/CU (was 2) for latency hiding on this short-work kernel.
// ---------------------------------------------------------------------------
__global__ __launch_bounds__(256, 3) void qkv_fast(const bf16* __restrict__ x,
                                                   const bf16* __restrict__ w,
                                                   bf16* __restrict__ qw,
                                                   bf16* __restrict__ kw,
                                                   f16* __restrict__ vtw)
{
    __shared__ short w_s[64][264];
    __shared__ f16 vts[64][68];
    const int tid  = threadIdx.x;
    const int lane = tid & 63;
    const int wav  = tid >> 6;
    const int quad = lane >> 4;
    const int l16  = lane & 15;
    const int bid = (blockIdx.x & 7) * 192 + (blockIdx.x >> 3);   // 1536 = 8*192
    const int mt = bid / 12, nb = bid % 12;
    const int m0 = mt * 128, n0 = nb * 64;

    {
        const int row = tid >> 2, cb = (tid & 3) * 64;
        const bf16* src = w + (size_t)(n0 + row) * C_ + cb;
#pragma unroll
        for (int i = 0; i < 8; ++i)
            *reinterpret_cast<bf16x8*>(&w_s[row][cb + i * 8]) =
                *reinterpret_cast<const bf16x8*>(src + i * 8);
    }
    __syncthreads();

#pragma unroll
    for (int half = 0; half < 2; ++half) {
        const int mh = m0 + half * 64;
        f32x4 acc[4] = {{0,0,0,0},{0,0,0,0},{0,0,0,0},{0,0,0,0}};
        const bf16* xrow = x + (size_t)(mh + wav * 16 + l16) * C_ + quad * 8;
        if (nb < 8) {        // Q/K: transposed accumulator (swapped operands)
#pragma unroll
            for (int k0 = 0; k0 < C_; k0 += 32) {
                bf16x8 a = *reinterpret_cast<const bf16x8*>(xrow + k0);
#pragma unroll
                for (int nt = 0; nt < 4; ++nt) {
                    bf16x8 b = *reinterpret_cast<const bf16x8*>(&w_s[nt * 16 + l16][k0 + quad * 8]);
                    acc[nt] = __builtin_amdgcn_mfma_f32_16x16x32_bf16(b, a, acc[nt], 0, 0, 0);
                }
            }
        } else {             // V: normal orientation
#pragma unroll
            for (int k0 = 0; k0 < C_; k0 += 32) {
                bf16x8 a = *reinterpret_cast<const bf16x8*>(xrow + k0);
#pragma unroll
                for (int nt = 0; nt < 4; ++nt) {
                    bf16x8 b = *reinterpret_cast<const bf16x8*>(&w_s[nt * 16 + l16][k0 + quad * 8]);
                    acc[nt] = __builtin_amdgcn_mfma_f32_16x16x32_bf16(a, b, acc[nt], 0, 0, 0);
                }
            }
        }

        const int bb = mh >> 12;
        const int nbase = (mh + wav * 16) & (N_ - 1);
        if (nb < 4) {                            // Q (scaled): row n = nbase+l16
            bf16* dst = qw + (((size_t)bb * H_ + nb) * N_ + nbase + l16) * D_;
#pragma unroll
            for (int nt = 0; nt < 4; ++nt) {
                u32x2 wv = { pk2(acc[nt][0] * KLN, acc[nt][1] * KLN),
                             pk2(acc[nt][2] * KLN, acc[nt][3] * KLN) };
                *reinterpret_cast<u32x2*>(dst + nt * 16 + quad * 4) = wv;
            }
        } else if (nb < 8) {                     // K
            bf16* dst = kw + (((size_t)bb * H_ + (nb - 4)) * N_ + nbase + l16) * D_;
#pragma unroll
            for (int nt = 0; nt < 4; ++nt) {
                u32x2 wv = { pk2(acc[nt][0], acc[nt][1]),
                             pk2(acc[nt][2], acc[nt][3]) };
                *reinterpret_cast<u32x2*>(dst + nt * 16 + quad * 4) = wv;
            }
        } else {                                 // V^T via LDS transpose
            const int h = nb - 8;
#pragma unroll
            for (int nt = 0; nt < 4; ++nt) {
                u32x2 wv = { pkh2(acc[nt][0], acc[nt][1]),
                             pkh2(acc[nt][2], acc[nt][3]) };
                *reinterpret_cast<u32x2*>(&vts[nt * 16 + l16][wav * 16 + quad * 4]) = wv;
            }
            __syncthreads();
            const int nloc = mh & (N_ - 1);
#pragma unroll
            for (int rep = 0; rep < 2; ++rep) {
                const int d  = (tid >> 3) + rep * 32;
                const int nc = (tid & 7) * 8;
                f16x8 vv = *reinterpret_cast<const f16x8*>(&vts[d][nc]);
                *reinterpret_cast<f16x8*>(
                    vtw + (((size_t)bb * H_ + h) * D_ + d) * N_ + nloc + nc) = vv;
            }
            __syncthreads();   // vts reused by the next half
        }
    }
}

// ---------------------------------------------------------------------------
// Flash attention v9 (hardened resubmit; r5 run died to container infra).
//  - K on the DMA->LDS double-buffer path (full-tile prefetch slack; r4
//    proved direct K loads stall on L2 latency). pi row-permutation and
//    XOR chunk swizzle unchanged.
//  - V in registers (r4 proved this is latency-safe: vf for t+1 reloads
//    during PV of t, used a full QK+exp phase later). No V LDS traffic.
//  - Counted per-tile sync: s_waitcnt vmcnt(8) lgkmcnt(0) + raw s_barrier.
//    HARDENING vs r5: sched_barrier(0) immediately after each stageK pins
//    the 4 K-DMAs as the oldest outstanding vmem ops, so vmcnt(8) provably
//    drains K while the 8 newer vf loads stay in flight (without the pin,
//    the compiler may hoist vf reloads above the DMA and break the count).
// Block = 4 waves = 2 q-subtiles (64 rows, 4 q-groups) x 2 j-halves.
// Grid 512 = 2 blocks/CU. Bit-identical arithmetic to r3/r4.
// ---------------------------------------------------------------------------
__global__ __launch_bounds__(256, 2) void attn(const bf16* __restrict__ q,
                                               const bf16* __restrict__ k,
                                               const f16* __restrict__ vt,
                                               bf16* __restrict__ o)
{
    __shared__ __align__(16) char smem[35328];   // k_s (32KB) / mrg overlay
    short* k_s = reinterpret_cast<short*>(smem);            // [buf][jh][64*64]

    const int tid  = threadIdx.x;
    const int lane = tid & 63;
    const int wav  = tid >> 6;       // 0..3
    const int quad = lane >> 4;
    const int l16  = lane & 15;
    const int l8   = lane & 7;
    const int sub  = wav & 1;        // 64-row q-slice within the 128-row tile
    const int jh   = wav >> 1;       // j-half

    const int wg = (blockIdx.x & 7) * 64 + (blockIdx.x >> 3);  // XCD swizzle
    const int bh = wg >> 5;
    const int qt = wg & 31;
    const int bb = bh >> 2, h = bh & 3;

    const bf16* qp = q  + (size_t)bh * N_ * D_;
    const bf16* kp = k  + (size_t)bh * N_ * D_;
    const f16*  vp = vt + (size_t)bh * D_ * N_;

    const int qbase = qt * 128 + sub * 64;
    bf16x8 qb[4][2];
#pragma unroll
    for (int qg = 0; qg < 4; ++qg)
#pragma unroll
        for (int ks = 0; ks < 2; ++ks)
            qb[qg][ks] = *reinterpret_cast<const bf16x8*>(
                qp + (size_t)(qbase + qg * 16 + l16) * D_ + ks * 32 + quad * 8);

    // K staging geometry: lane -> (row ri, stored slot ci); chunk = ci^ri
    const int ri = lane >> 3;
    const int ci = lane & 7;
    const int gc = ci ^ ri;
    int koff[4], lds_r[4];
#pragma unroll
    for (int g = 0; g < 4; ++g) {
        const int rb  = sub * 32 + g * 8;        // this wave stages 32 K rows
        const int rho = rb + ri;
        const int pr  = (rho & 32) | ((rho & 12) << 1) | ((rho & 16) >> 2) | (rho & 3);
        koff[g]  = pr * D_ + gc * 8;             // pi-permuted row, swizzled chunk
        lds_r[g] = rb * 64;
    }

    f32x4 oacc[4][4];
    f32x4 lv[4];
#pragma unroll
    for (int qg = 0; qg < 4; ++qg) {
        lv[qg] = (f32x4){0, 0, 0, 0};
#pragma unroll
        for (int dt = 0; dt < 4; ++dt) oacc[qg][dt] = (f32x4){0, 0, 0, 0};
    }

    const int j00 = jh * 2048;

    auto stageK = [&](int buf, int t) {
        const int j0 = j00 + t * 64;
        short* kd = k_s + (size_t)(buf * 2 + jh) * 4096;
#pragma unroll
        for (int g = 0; g < 4; ++g)
            load_lds16(kp + (size_t)j0 * D_ + koff[g], kd + lds_r[g]);
    };

    // prologue: K(0) DMA first (pinned oldest), then vf(0) loads (8 newest)
    stageK(0, 0);
    __builtin_amdgcn_sched_barrier(0);     // pin: K DMA issued before vf loads
    f16x8 vf[2][4];
#pragma unroll
    for (int ks = 0; ks < 2; ++ks)
#pragma unroll
        for (int dt = 0; dt < 4; ++dt)
            vf[ks][dt] = *reinterpret_cast<const f16x8*>(
                vp + (size_t)(dt * 16 + l16) * N_ + j00 + (ks * 4 + quad) * 8);
    asm volatile("s_waitcnt vmcnt(8)" ::: "memory");   // K(0) done, vf in flight
    __builtin_amdgcn_sched_barrier(0);
    __builtin_amdgcn_s_barrier();

    for (int t = 0; t < 32; ++t) {
        const int cur = t & 1;
        if (t < 31) stageK(cur ^ 1, t + 1);   // 4 DMA, full tile to land
        __builtin_amdgcn_sched_barrier(0);    // pin: K DMA oldest this tile

        const short* kt = k_s + (size_t)(cur * 2 + jh) * 4096;
        const int jn = j00 + (t + 1) * 64;

        // S^T = K.Q^T; p = exp2(s) -> f16 B-fragments in registers
        f16x8 pb[4][2];
#pragma unroll
        for (int nt = 0; nt < 4; ++nt) {
            const int rb = (nt * 16 + l16) * 64;
            bf16x8 k0 = *reinterpret_cast<const bf16x8*>(kt + rb + ((quad    ) ^ l8) * 8);
            bf16x8 k1 = *reinterpret_cast<const bf16x8*>(kt + rb + ((4 + quad) ^ l8) * 8);
#pragma unroll
            for (int qg = 0; qg < 4; ++qg) {
                f32x4 sv = __builtin_amdgcn_mfma_f32_16x16x32_bf16(
                    k0, qb[qg][0], (f32x4){0.f, 0.f, 0.f, 0.f}, 0, 0, 0);
                sv = __builtin_amdgcn_mfma_f32_16x16x32_bf16(
                    k1, qb[qg][1], sv, 0, 0, 0);
                f32x4 pa = { EXP2(sv[0]), EXP2(sv[1]), EXP2(sv[2]), EXP2(sv[3]) };
                u32x2 pw = { pkh2(pa[0], pa[1]), pkh2(pa[2], pa[3]) };
                if (nt & 1)
                    *(reinterpret_cast<u32x2*>(&pb[qg][nt >> 1]) + 1) = pw;
                else
                    *(reinterpret_cast<u32x2*>(&pb[qg][nt >> 1]) + 0) = pw;
                lv[qg] += pa;
            }
        }

        // O^T += V^T . P^T; reload each vf for t+1 right after its last use
#pragma unroll
        for (int ks = 0; ks < 2; ++ks)
#pragma unroll
            for (int dt = 0; dt < 4; ++dt) {
                const f16x8 va = vf[ks][dt];
#pragma unroll
                for (int qg = 0; qg < 4; ++qg)
                    oacc[qg][dt] = __builtin_amdgcn_mfma_f32_16x16x32_f16(
                        va, pb[qg][ks], oacc[qg][dt], 0, 0, 0);
                if (t < 31)
                    vf[ks][dt] = *reinterpret_cast<const f16x8*>(
                        vp + (size_t)(dt * 16 + l16) * N_ + jn + (ks * 4 + quad) * 8);
            }

        // counted sync: drain my K(t+1) DMA (oldest 4) + my LDS reads; the
        // 8 vf(t+1) loads stay in flight across the barrier.
        asm volatile("s_waitcnt vmcnt(8) lgkmcnt(0)" ::: "memory");
        __builtin_amdgcn_sched_barrier(0);
        __builtin_amdgcn_s_barrier();
    }

    // l: horizontal sum + butterfly across the 4 quads (same l16 = same q-row)
    float lr[4];
#pragma unroll
    for (int qg = 0; qg < 4; ++qg) {
        float l = (lv[qg][0] + lv[qg][1]) + (lv[qg][2] + lv[qg][3]);
        l += __shfl_xor(l, 16);
        l += __shfl_xor(l, 32);
        lr[qg] = l;
    }

    // ---- merge j-halves (exact: O and l add) via lane-to-lane LDS slots ----
    float* mrg = reinterpret_cast<float*>(smem);   // k_s is dead
    const int slot = (sub * 64 + lane) * 69;       // odd stride: no conflicts
    __syncthreads();
    if (jh == 1) {
#pragma unroll
        for (int qg = 0; qg < 4; ++qg) {
#pragma unroll
            for (int dt = 0; dt < 4; ++dt)
#pragma unroll
                for (int e = 0; e < 4; ++e)
                    mrg[slot + qg * 17 + dt * 4 + e] = oacc[qg][dt][e];
            mrg[slot + qg * 17 + 16] = lr[qg];
        }
    }
    __syncthreads();
    if (jh == 0) {
#pragma unroll
        for (int qg = 0; qg < 4; ++qg) {
            const float rl = RCP(lr[qg] + mrg[slot + qg * 17 + 16]);
            const size_t obase = ((size_t)bb * N_ + qbase + qg * 16 + l16) * C_ + h * D_;
#pragma unroll
            for (int dt = 0; dt < 4; ++dt) {
                float v0 = (oacc[qg][dt][0] + mrg[slot + qg * 17 + dt * 4 + 0]) * rl;
                float v1 = (oacc[qg][dt][1] + mrg[slot + qg * 17 + dt * 4 + 1]) * rl;
                float v2 = (oacc[qg][dt][2] + mrg[slot + qg * 17 + dt * 4 + 2]) * rl;
                float v3 = (oacc[qg][dt][3] + mrg[slot + qg * 17 + dt * 4 + 3]) * rl;
                u32x2 wv = { pk2(v0, v1), pk2(v2, v3) };
                *reinterpret_cast<u32x2*>(o + obase + dt * 16 + quad * 4) = wv;
            }
        }
    }
}

// ---------------------------------------------------------------------------
// Output projection, W staged in LDS once per 128-row m-tile. Swapped MFMA
// operands -> transposed accumulator -> f32x4 stores. launch_bounds(256,4):
// LDS 33.8KB -> 4 blocks/CU for latency hiding.
// ---------------------------------------------------------------------------
__global__ __launch_bounds__(256, 4) void out_proj_fast(const bf16* __restrict__ ov,
                                                        const bf16* __restrict__ w,
                                                        const float* __restrict__ bias,
                                                        float* __restrict__ out)
{
    __shared__ short w_s[64][264];
    const int tid  = threadIdx.x;
    const int lane = tid & 63;
    const int wav  = tid >> 6;
    const int quad = lane >> 4;
    const int l16  = lane & 15;
    const int bid = (blockIdx.x & 7) * 64 + (blockIdx.x >> 3);   // 512 = 8*64
    const int m0 = (bid >> 2) * 128;
    const int n0 = (bid & 3) * 64;

    {
        const int row = tid >> 2, cb = (tid & 3) * 64;
        const bf16* src = w + (size_t)(n0 + row) * C_ + cb;
#pragma unroll
        for (int i = 0; i < 8; ++i)
            *reinterpret_cast<bf16x8*>(&w_s[row][cb + i * 8]) =
                *reinterpret_cast<const bf16x8*>(src + i * 8);
    }
    __syncthreads();

#pragma unroll
    for (int half = 0; half < 2; ++half) {
        const int mh = m0 + half * 64;
        f32x4 acc[4] = {{0,0,0,0},{0,0,0,0},{0,0,0,0},{0,0,0,0}};
        const bf16* orow = ov + (size_t)(mh + wav * 16 + l16) * C_ + quad * 8;
#pragma unroll
        for (int k0 = 0; k0 < C_; k0 += 32) {
            bf16x8 a = *reinterpret_cast<const bf16x8*>(orow + k0);
#pragma unroll
            for (int nt = 0; nt < 4; ++nt) {
                bf16x8 b = *reinterpret_cast<const bf16x8*>(&w_s[nt * 16 + l16][k0 + quad * 8]);
                acc[nt] = __builtin_amdgcn_mfma_f32_16x16x32_bf16(b, a, acc[nt], 0, 0, 0);
            }
        }
        const int m = mh + wav * 16 + l16;
#pragma unroll
        for (int nt = 0; nt < 4; ++nt) {
            const int oc0 = n0 + nt * 16 + quad * 4;
            f32x4 bv = *reinterpret_cast<const f32x4*>(bias + oc0);
            f32x4 ovv = acc[nt] + bv;
            *reinterpret_cast<f32x4*>(out + (size_t)m * C_ + oc0) = ovv;
        }
    }
}

extern "C" void kernel_launch(void* const* d_in, const int* in_sizes, int n_in,
                              void* d_out, int out_size, void* d_ws, size_t ws_size,
                              hipStream_t stream) {
    const float* x      = (const float*)d_in[0];
    const float* w_qkv  = (const float*)d_in[1];
    const float* w_proj = (const float*)d_in[2];
    const float* b_proj = (const float*)d_in[3];
    float* out = (float*)d_out;

    const size_t qkv_elems = (size_t)B_ * H_ * N_ * D_;   // 4,194,304
    bf16* q_ws  = (bf16*)d_ws;
    bf16* k_ws  = q_ws  + qkv_elems;
    f16*  vt_ws = (f16*)(k_ws + qkv_elems);
    bf16* o_ws  = (bf16*)(vt_ws + qkv_elems);
    bf16* x_bf  = o_ws  + qkv_elems;
    bf16* wq_bf = x_bf  + (size_t)B_ * N_ * C_;
    bf16* wp_bf = wq_bf + (size_t)3 * C_ * C_;

    cast_bf16    <<<2176, 256, 0, stream>>>(x, w_qkv, w_proj, x_bf, wq_bf, wp_bf);
    qkv_fast     <<<1536, 256, 0, stream>>>(x_bf, wq_bf, q_ws, k_ws, vt_ws);
    attn         <<< 512, 256, 0, stream>>>(q_ws, k_ws, vt_ws, o_ws);
    out_proj_fast<<< 512, 256, 0, stream>>>(o_ws, wp_bf, b_proj, out);
}

// Round 7
// 171.979 us; speedup vs baseline: 1.4017x; 1.1619x over previous
//
#include <hip/hip_runtime.h>
#include <hip/hip_bf16.h>

typedef __hip_bfloat16 bf16;
typedef _Float16 f16;
typedef __attribute__((ext_vector_type(8))) short bf16x8;
typedef __attribute__((ext_vector_type(8))) _Float16 f16x8;
typedef __attribute__((ext_vector_type(2))) _Float16 f16x2;
typedef __attribute__((ext_vector_type(4))) float f32x4;
typedef __attribute__((ext_vector_type(4))) unsigned int u32x4;
typedef __attribute__((ext_vector_type(2))) unsigned int u32x2;

#define B_ 4
#define N_ 4096
#define C_ 256
#define H_ 4
#define D_ 64
#define KLN 0.18033688011112042f   /* 0.125 * log2(e): folded into Q */

#if __has_builtin(__builtin_amdgcn_exp2f)
#define EXP2(x) __builtin_amdgcn_exp2f(x)
#else
#define EXP2(x) exp2f(x)
#endif
#if __has_builtin(__builtin_amdgcn_rcpf)
#define RCP(x) __builtin_amdgcn_rcpf(x)
#else
#define RCP(x) (1.0f / (x))
#endif

// direct global->LDS DMA, 16B per lane. LDS dest = wave-uniform base + lane*16.
__device__ inline void load_lds16(const void* g, void* l) {
#if __has_builtin(__builtin_amdgcn_global_load_lds)
    __builtin_amdgcn_global_load_lds(
        (const __attribute__((address_space(1))) unsigned int*)g,
        (__attribute__((address_space(3))) unsigned int*)l, 16, 0, 0);
#else
    int ln = __lane_id();
    ((u32x4*)l)[ln] = *((const u32x4*)g);   // fallback (not used on gfx950)
#endif
}

// two fp32 -> packed bf16 pair (round-half-up)
__device__ inline unsigned int pk2(float a, float b) {
    unsigned int ua = __builtin_bit_cast(unsigned int, a) + 0x8000u;
    unsigned int ub = __builtin_bit_cast(unsigned int, b) + 0x8000u;
    return (ua >> 16) | (ub & 0xffff0000u);
}
// two fp32 -> packed f16 pair (single v_cvt_pkrtz_f16_f32)
__device__ inline unsigned int pkh2(float a, float b) {
#if __has_builtin(__builtin_amdgcn_cvt_pkrtz)
    return __builtin_bit_cast(unsigned int, __builtin_amdgcn_cvt_pkrtz(a, b));
#else
    f16x2 h = { (f16)a, (f16)b };
    return __builtin_bit_cast(unsigned int, h);
#endif
}

// ---------------------------------------------------------------------------
// Prep: cast x, w_qkv, w_proj fp32 -> bf16 (memory-bound).
// ---------------------------------------------------------------------------
__global__ __launch_bounds__(256) void cast_bf16(const float* __restrict__ x,
                                                 const float* __restrict__ wq,
                                                 const float* __restrict__ wp,
                                                 bf16* __restrict__ xb,
                                                 bf16* __restrict__ wqb,
                                                 bf16* __restrict__ wpb)
{
    int bid = blockIdx.x;
    const float* s; bf16* d; int base;
    if (bid < 2048)      { s = x;  d = xb;  base = bid * 2048; }
    else if (bid < 2144) { s = wq; d = wqb; base = (bid - 2048) * 2048; }
    else                 { s = wp; d = wpb; base = (bid - 2144) * 2048; }
    int i = base + threadIdx.x * 8;
    f32x4 a = *reinterpret_cast<const f32x4*>(s + i);
    f32x4 b = *reinterpret_cast<const f32x4*>(s + i + 4);
    u32x4 o;
    o.x = pk2(a[0], a[1]); o.y = pk2(a[2], a[3]);
    o.z = pk2(b[0], b[1]); o.w = pk2(b[2], b[3]);
    *reinterpret_cast<u32x4*>(d + i) = o;
}

// ---------------------------------------------------------------------------
// QKV projection — exact round-3 version (best measured non-attn config).
// W staged in LDS once per 128-row m-tile; Q pre-scaled by KLN; V -> [B,H,D,N]
// f16 direct store. Q/K swapped MFMA operands -> transposed acc -> u32x2
// stores. XCD swizzle groups the 12 n-tiles of one m-tile per XCD.
// ---------------------------------------------------------------------------
__global__ __launch_bounds__(256, 2) void qkv_fast(const bf16* __restrict__ x,
                                                   const bf16* __restrict__ w,
                                                   bf16* __restrict__ qw,
                                                   bf16* __restrict__ kw,
                                                   f16* __restrict__ vtw)
{
    __shared__ short w_s[64][264];
    const int tid  = threadIdx.x;
    const int lane = tid & 63;
    const int wav  = tid >> 6;
    const int quad = lane >> 4;
    const int l16  = lane & 15;
    const int bid = (blockIdx.x & 7) * 192 + (blockIdx.x >> 3);   // 1536 = 8*192
    const int mt = bid / 12, nb = bid % 12;
    const int m0 = mt * 128, n0 = nb * 64;

    {
        const int row = tid >> 2, cb = (tid & 3) * 64;
        const bf16* src = w + (size_t)(n0 + row) * C_ + cb;
#pragma unroll
        for (int i = 0; i < 8; ++i)
            *reinterpret_cast<bf16x8*>(&w_s[row][cb + i * 8]) =
                *reinterpret_cast<const bf16x8*>(src + i * 8);
    }
    __syncthreads();

#pragma unroll
    for (int half = 0; half < 2; ++half) {
        const int mh = m0 + half * 64;
        f32x4 acc[4] = {{0,0,0,0},{0,0,0,0},{0,0,0,0},{0,0,0,0}};
        const bf16* xrow = x + (size_t)(mh + wav * 16 + l16) * C_ + quad * 8;
        if (nb < 8) {        // Q/K: transposed accumulator (swapped operands)
#pragma unroll
            for (int k0 = 0; k0 < C_; k0 += 32) {
                bf16x8 a = *reinterpret_cast<const bf16x8*>(xrow + k0);
#pragma unroll
                for (int nt = 0; nt < 4; ++nt) {
                    bf16x8 b = *reinterpret_cast<const bf16x8*>(&w_s[nt * 16 + l16][k0 + quad * 8]);
                    acc[nt] = __builtin_amdgcn_mfma_f32_16x16x32_bf16(b, a, acc[nt], 0, 0, 0);
                }
            }
        } else {             // V: normal orientation (store wants n-contiguous)
#pragma unroll
            for (int k0 = 0; k0 < C_; k0 += 32) {
                bf16x8 a = *reinterpret_cast<const bf16x8*>(xrow + k0);
#pragma unroll
                for (int nt = 0; nt < 4; ++nt) {
                    bf16x8 b = *reinterpret_cast<const bf16x8*>(&w_s[nt * 16 + l16][k0 + quad * 8]);
                    acc[nt] = __builtin_amdgcn_mfma_f32_16x16x32_bf16(a, b, acc[nt], 0, 0, 0);
                }
            }
        }

        const int bb = mh >> 12;
        const int nbase = (mh + wav * 16) & (N_ - 1);
        if (nb < 4) {                            // Q (scaled): row n = nbase+l16
            bf16* dst = qw + (((size_t)bb * H_ + nb) * N_ + nbase + l16) * D_;
#pragma unroll
            for (int nt = 0; nt < 4; ++nt) {
                u32x2 wv = { pk2(acc[nt][0] * KLN, acc[nt][1] * KLN),
                             pk2(acc[nt][2] * KLN, acc[nt][3] * KLN) };
                *reinterpret_cast<u32x2*>(dst + nt * 16 + quad * 4) = wv;
            }
        } else if (nb < 8) {                     // K
            bf16* dst = kw + (((size_t)bb * H_ + (nb - 4)) * N_ + nbase + l16) * D_;
#pragma unroll
            for (int nt = 0; nt < 4; ++nt) {
                u32x2 wv = { pk2(acc[nt][0], acc[nt][1]),
                             pk2(acc[nt][2], acc[nt][3]) };
                *reinterpret_cast<u32x2*>(dst + nt * 16 + quad * 4) = wv;
            }
        } else {                                 // V transposed, f16
            const int h = nb - 8;
#pragma unroll
            for (int nt = 0; nt < 4; ++nt) {
                int d = nt * 16 + l16;
                u32x2 wv;
                wv.x = pkh2(acc[nt][0], acc[nt][1]);
                wv.y = pkh2(acc[nt][2], acc[nt][3]);
                *reinterpret_cast<u32x2*>(
                    vtw + (((size_t)bb * H_ + h) * D_ + d) * N_ + nbase + quad * 4) = wv;
            }
        }
    }
}

// ---------------------------------------------------------------------------
// Flash attention v10 = r1 structure (best measured: 72.1us, 8-wave 512-thr
// blocks, 2 q-groups/wave, K+V LDS double-buffer, one __syncthreads/tile,
// in-register P via pi K-row permutation, l via ones-MFMA) with ONE change:
// the per-tile body is REORDERED (bit-identical ops) to interleave the
// independent matrix/VALU streams:
//     QK(0) -> exp(0)+l(0) -> QK(1) -> PV(0) -> exp(1)+l(1) -> PV(1)
// exp(1)'s VALU block issues behind the 24-MFMA QK(1)+PV(0) backlog and
// executes while it drains; PV(1) executes under the next tile's staging +
// ds_reads. r1's counters (MfmaUtil 47.8 + VALUBusy 48.4, ~no overlap)
// showed these phases serializing; this exposes the overlap to the issue
// order without any new state (one live S array; VGPR stays ~r1 budget).
// ---------------------------------------------------------------------------
__global__ __launch_bounds__(512, 4) void attn(const bf16* __restrict__ q,
                                               const bf16* __restrict__ k,
                                               const f16* __restrict__ vt,
                                               bf16* __restrict__ o)
{
    __shared__ __align__(16) char smem[65536];
    short* k_s = reinterpret_cast<short*>(smem);            // [buf][jh][64*64]
    f16*   v_s = reinterpret_cast<f16*>(smem + 32768);      // [buf][jh][64*64]

    const int tid  = threadIdx.x;
    const int lane = tid & 63;
    const int wav  = tid >> 6;       // 0..7
    const int quad = lane >> 4;
    const int l16  = lane & 15;
    const int l8   = lane & 7;
    const int sub  = wav & 3;        // 32-row q-slice within the 128-row tile
    const int jh   = wav >> 2;       // j-half

    const int wg = (blockIdx.x & 7) * 64 + (blockIdx.x >> 3);  // XCD swizzle
    const int bh = wg >> 5;
    const int qt = wg & 31;
    const int bb = bh >> 2, h = bh & 3;

    const bf16* qp = q  + (size_t)bh * N_ * D_;
    const bf16* kp = k  + (size_t)bh * N_ * D_;
    const f16*  vp = vt + (size_t)bh * D_ * N_;

    const int qbase = qt * 128 + sub * 32;
    bf16x8 qb[2][2];
#pragma unroll
    for (int qg = 0; qg < 2; ++qg)
#pragma unroll
        for (int ks = 0; ks < 2; ++ks)
            qb[qg][ks] = *reinterpret_cast<const bf16x8*>(
                qp + (size_t)(qbase + qg * 16 + l16) * D_ + ks * 32 + quad * 8);

    // staging geometry: lane -> (row ri, stored slot ci); logical chunk = ci^ri
    const int ri = lane >> 3;
    const int ci = lane & 7;
    const int gc = ci ^ ri;
    int koff[2], voff[2], lds_r[2];
#pragma unroll
    for (int g = 0; g < 2; ++g) {
        const int rb  = sub * 16 + g * 8;
        const int rho = rb + ri;
        const int pr  = (rho & 32) | ((rho & 12) << 1) | ((rho & 16) >> 2) | (rho & 3);
        koff[g]  = pr * D_ + gc * 8;          // K: permuted row, swizzled chunk
        voff[g]  = rho * N_ + gc * 8;         // V: linear d-row, swizzled chunk
        lds_r[g] = rb * 64;
    }

    f32x4 oacc[2][4];
    f32x4 lacc[2];
#pragma unroll
    for (int qg = 0; qg < 2; ++qg) {
        lacc[qg] = (f32x4){0, 0, 0, 0};
#pragma unroll
        for (int dt = 0; dt < 4; ++dt) oacc[qg][dt] = (f32x4){0, 0, 0, 0};
    }
    const f16x8 onesA = {1.f16, 1.f16, 1.f16, 1.f16, 1.f16, 1.f16, 1.f16, 1.f16};

    auto stage = [&](int buf, int t) {
        const int j0 = jh * 2048 + t * 64;
        short* kd = k_s + (size_t)(buf * 2 + jh) * 4096;
        f16*   vd = v_s + (size_t)(buf * 2 + jh) * 4096;
#pragma unroll
        for (int g = 0; g < 2; ++g) {
            load_lds16(kp + (size_t)j0 * D_ + koff[g], kd + lds_r[g]);
            load_lds16(vp + j0 + voff[g],              vd + lds_r[g]);
        }
    };

    stage(0, 0);
    __syncthreads();

    for (int t = 0; t < 32; ++t) {
        const int cur = t & 1;
        if (t < 31) stage(cur ^ 1, t + 1);    // DMA overlaps this tile's compute

        const short* kt  = k_s + (size_t)(cur * 2 + jh) * 4096;
        const f16*   vtl = v_s + (size_t)(cur * 2 + jh) * 4096;

        // K fragments (shared across both q-groups)
        bf16x8 ka[4][2];
#pragma unroll
        for (int nt = 0; nt < 4; ++nt) {
            const int rb = (nt * 16 + l16) * 64;
            ka[nt][0] = *reinterpret_cast<const bf16x8*>(kt + rb + ((quad    ) ^ l8) * 8);
            ka[nt][1] = *reinterpret_cast<const bf16x8*>(kt + rb + ((4 + quad) ^ l8) * 8);
        }

        f32x4 s[4];
        f16x8 pb0[2], pb1[2];

        // --- QK(0) ---
#pragma unroll
        for (int nt = 0; nt < 4; ++nt) {
            s[nt] = __builtin_amdgcn_mfma_f32_16x16x32_bf16(
                ka[nt][0], qb[0][0], (f32x4){0.f, 0.f, 0.f, 0.f}, 0, 0, 0);
            s[nt] = __builtin_amdgcn_mfma_f32_16x16x32_bf16(
                ka[nt][1], qb[0][1], s[nt], 0, 0, 0);
        }
        // --- exp(0) + l(0) ---
#pragma unroll
        for (int ks = 0; ks < 2; ++ks) {
            const f32x4 sa = s[2 * ks], sb = s[2 * ks + 1];
            u32x4 pw;
            pw.x = pkh2(EXP2(sa[0]), EXP2(sa[1]));
            pw.y = pkh2(EXP2(sa[2]), EXP2(sa[3]));
            pw.z = pkh2(EXP2(sb[0]), EXP2(sb[1]));
            pw.w = pkh2(EXP2(sb[2]), EXP2(sb[3]));
            pb0[ks] = __builtin_bit_cast(f16x8, pw);
            lacc[0] = __builtin_amdgcn_mfma_f32_16x16x32_f16(onesA, pb0[ks], lacc[0], 0, 0, 0);
        }
        // --- QK(1) (matrix; independent of exp(0)/PV(0)) ---
#pragma unroll
        for (int nt = 0; nt < 4; ++nt) {
            s[nt] = __builtin_amdgcn_mfma_f32_16x16x32_bf16(
                ka[nt][0], qb[1][0], (f32x4){0.f, 0.f, 0.f, 0.f}, 0, 0, 0);
            s[nt] = __builtin_amdgcn_mfma_f32_16x16x32_bf16(
                ka[nt][1], qb[1][1], s[nt], 0, 0, 0);
        }
        // --- PV(0) (matrix; queues behind QK(1)) ---
#pragma unroll
        for (int ks = 0; ks < 2; ++ks)
#pragma unroll
            for (int dt = 0; dt < 4; ++dt) {
                f16x8 va = *reinterpret_cast<const f16x8*>(
                    vtl + (dt * 16 + l16) * 64 + (((ks << 2) + quad) ^ l8) * 8);
                oacc[0][dt] = __builtin_amdgcn_mfma_f32_16x16x32_f16(va, pb0[ks], oacc[0][dt], 0, 0, 0);
            }
        // --- exp(1) + l(1) (VALU; executes under the QK(1)+PV(0) backlog) ---
#pragma unroll
        for (int ks = 0; ks < 2; ++ks) {
            const f32x4 sa = s[2 * ks], sb = s[2 * ks + 1];
            u32x4 pw;
            pw.x = pkh2(EXP2(sa[0]), EXP2(sa[1]));
            pw.y = pkh2(EXP2(sa[2]), EXP2(sa[3]));
            pw.z = pkh2(EXP2(sb[0]), EXP2(sb[1]));
            pw.w = pkh2(EXP2(sb[2]), EXP2(sb[3]));
            pb1[ks] = __builtin_bit_cast(f16x8, pw);
            lacc[1] = __builtin_amdgcn_mfma_f32_16x16x32_f16(onesA, pb1[ks], lacc[1], 0, 0, 0);
        }
        // --- PV(1) (matrix; executes under next tile's staging + reads) ---
#pragma unroll
        for (int ks = 0; ks < 2; ++ks)
#pragma unroll
            for (int dt = 0; dt < 4; ++dt) {
                f16x8 va = *reinterpret_cast<const f16x8*>(
                    vtl + (dt * 16 + l16) * 64 + (((ks << 2) + quad) ^ l8) * 8);
                oacc[1][dt] = __builtin_amdgcn_mfma_f32_16x16x32_f16(va, pb1[ks], oacc[1][dt], 0, 0, 0);
            }

        __syncthreads();   // drains this wave's DMA (t+1) + fences buf reads
    }

    // ---- merge j-halves (exact: O and l add) via lane-to-lane LDS slots ----
    __syncthreads();                  // staging reads done; reuse as merge buf
    float* mrg = reinterpret_cast<float*>(smem);
    const int slot = (sub * 64 + lane) * 35;       // odd stride: no conflicts
    if (jh == 1) {
#pragma unroll
        for (int qg = 0; qg < 2; ++qg) {
#pragma unroll
            for (int dt = 0; dt < 4; ++dt)
#pragma unroll
                for (int e = 0; e < 4; ++e)
                    mrg[slot + qg * 17 + dt * 4 + e] = oacc[qg][dt][e];
            mrg[slot + qg * 17 + 16] = lacc[qg][0];
        }
    }
    __syncthreads();
    if (jh == 0) {
#pragma unroll
        for (int qg = 0; qg < 2; ++qg) {
            const float rl = RCP(lacc[qg][0] + mrg[slot + qg * 17 + 16]);
            const size_t obase = ((size_t)bb * N_ + qbase + qg * 16 + l16) * C_ + h * D_;
#pragma unroll
            for (int dt = 0; dt < 4; ++dt) {
                float v0 = (oacc[qg][dt][0] + mrg[slot + qg * 17 + dt * 4 + 0]) * rl;
                float v1 = (oacc[qg][dt][1] + mrg[slot + qg * 17 + dt * 4 + 1]) * rl;
                float v2 = (oacc[qg][dt][2] + mrg[slot + qg * 17 + dt * 4 + 2]) * rl;
                float v3 = (oacc[qg][dt][3] + mrg[slot + qg * 17 + dt * 4 + 3]) * rl;
                u32x2 wv = { pk2(v0, v1), pk2(v2, v3) };
                *reinterpret_cast<u32x2*>(o + obase + dt * 16 + quad * 4) = wv;
            }
        }
    }
}

// ---------------------------------------------------------------------------
// Output projection — exact round-3 version. W staged in LDS once per
// 128-row m-tile; swapped MFMA operands -> transposed acc -> f32x4 stores.
// ---------------------------------------------------------------------------
__global__ __launch_bounds__(256, 2) void out_proj_fast(const bf16* __restrict__ ov,
                                                        const bf16* __restrict__ w,
                                                        const float* __restrict__ bias,
                                                        float* __restrict__ out)
{
    __shared__ short w_s[64][264];
    const int tid  = threadIdx.x;
    const int lane = tid & 63;
    const int wav  = tid >> 6;
    const int quad = lane >> 4;
    const int l16  = lane & 15;
    const int bid = (blockIdx.x & 7) * 64 + (blockIdx.x >> 3);   // 512 = 8*64
    const int m0 = (bid >> 2) * 128;
    const int n0 = (bid & 3) * 64;

    {
        const int row = tid >> 2, cb = (tid & 3) * 64;
        const bf16* src = w + (size_t)(n0 + row) * C_ + cb;
#pragma unroll
        for (int i = 0; i < 8; ++i)
            *reinterpret_cast<bf16x8*>(&w_s[row][cb + i * 8]) =
                *reinterpret_cast<const bf16x8*>(src + i * 8);
    }
    __syncthreads();

#pragma unroll
    for (int half = 0; half < 2; ++half) {
        const int mh = m0 + half * 64;
        f32x4 acc[4] = {{0,0,0,0},{0,0,0,0},{0,0,0,0},{0,0,0,0}};
        const bf16* orow = ov + (size_t)(mh + wav * 16 + l16) * C_ + quad * 8;
#pragma unroll
        for (int k0 = 0; k0 < C_; k0 += 32) {
            bf16x8 a = *reinterpret_cast<const bf16x8*>(orow + k0);
#pragma unroll
            for (int nt = 0; nt < 4; ++nt) {
                bf16x8 b = *reinterpret_cast<const bf16x8*>(&w_s[nt * 16 + l16][k0 + quad * 8]);
                acc[nt] = __builtin_amdgcn_mfma_f32_16x16x32_bf16(b, a, acc[nt], 0, 0, 0);
            }
        }
        const int m = mh + wav * 16 + l16;
#pragma unroll
        for (int nt = 0; nt < 4; ++nt) {
            const int oc0 = n0 + nt * 16 + quad * 4;
            f32x4 bv = *reinterpret_cast<const f32x4*>(bias + oc0);
            f32x4 ovv = acc[nt] + bv;
            *reinterpret_cast<f32x4*>(out + (size_t)m * C_ + oc0) = ovv;
        }
    }
}

extern "C" void kernel_launch(void* const* d_in, const int* in_sizes, int n_in,
                              void* d_out, int out_size, void* d_ws, size_t ws_size,
                              hipStream_t stream) {
    const float* x      = (const float*)d_in[0];
    const float* w_qkv  = (const float*)d_in[1];
    const float* w_proj = (const float*)d_in[2];
    const float* b_proj = (const float*)d_in[3];
    float* out = (float*)d_out;

    const size_t qkv_elems = (size_t)B_ * H_ * N_ * D_;   // 4,194,304
    bf16* q_ws  = (bf16*)d_ws;
    bf16* k_ws  = q_ws  + qkv_elems;
    f16*  vt_ws = (f16*)(k_ws + qkv_elems);
    bf16* o_ws  = (bf16*)(vt_ws + qkv_elems);
    bf16* x_bf  = o_ws  + qkv_elems;
    bf16* wq_bf = x_bf  + (size_t)B_ * N_ * C_;
    bf16* wp_bf = wq_bf + (size_t)3 * C_ * C_;

    cast_bf16    <<<2176, 256, 0, stream>>>(x, w_qkv, w_proj, x_bf, wq_bf, wp_bf);
    qkv_fast     <<<1536, 256, 0, stream>>>(x_bf, wq_bf, q_ws, k_ws, vt_ws);
    attn         <<< 512, 512, 0, stream>>>(q_ws, k_ws, vt_ws, o_ws);
    out_proj_fast<<< 512, 256, 0, stream>>>(o_ws, wp_bf, b_proj, out);
}